// Round 11
// baseline (112.849 us; speedup 1.0000x reference)
//
#include <hip/hip_runtime.h>
#include <math.h>

// ---------------- persistent LDS layout (floats) ----------------
#define LT_CT 0        // cT[25][32][4]: cT[c][l][u] = coef[l][4c+u], rows 30/31 zero
#define LT_WT 3200     // w[100] + pad
#define LT_SM 3304     // sm[292]
#define LT_AR 3600     // union arena (3792 floats)
#define LT_TOT 7392    // 29568 B

#define SM_WSUM 0
#define SM_RWS  1
#define SM_Q00  2
#define SM_Z2   4
#define SM_BS   16     // 32 slots (30 used)
#define SM_W    48
#define SM_G    148
#define SM_GV   248
#define SM_BW   260

// arena phase-A offsets (relative to LT_AR)
#define A_YS 0         // [8][304]  staged y (stride 304: item bases 16 banks apart, <=2-way)
#define A_SF 2432      // [8][97]   centered F (stride 97: conflict-free)
#define A_QL 3208      // [8][57]   Q upper-tri
#define A_AX 3664      // [8][16]   yw[3] @0, G3[9] @3

__host__ __device__ constexpr int TRI(int p,int q){ return p*10-(p*(p+1))/2+q; } // p<=q
__host__ __device__ constexpr int SIDX(int a,int b){ return (a<=b)?TRI(a,b):TRI(b,a); }
__host__ __device__ constexpr int LTRI(int i,int j){ return i*(i+1)/2+j; }       // j<=i

template<int CTRL>
__device__ __forceinline__ float dpp_add(float v){
  int s = __builtin_amdgcn_mov_dpp(__float_as_int(v), CTRL, 0xF, 0xF, true);
  return v + __int_as_float(s);
}
// 32-lane group sum: 4 DPP stages within 16 + xor-16 swizzle (verified R9)
__device__ __forceinline__ float gsum32(float v){
  v = dpp_add<0xB1>(v);    // quad xor1
  v = dpp_add<0x4E>(v);    // quad xor2
  v = dpp_add<0x141>(v);   // row_half_mirror
  v = dpp_add<0x140>(v);   // row_mirror (16-lane)
  v += __int_as_float(__builtin_amdgcn_ds_swizzle(__float_as_int(v), 0x401F)); // xor 16
  return v;
}

__global__ __launch_bounds__(256,4) void pace_fused(const float* __restrict__ y,
                                                    const float* __restrict__ w,
                                                    const float* __restrict__ mk,
                                                    float* __restrict__ out){
  __shared__ __attribute__((aligned(16))) float S[LT_TOT];
  const int tid  = threadIdx.x;
  const int lane = tid & 63;
  const int sub  = tid & 31;      // lane within item
  const int item = tid >> 5;      // 0..7

  // ================= Phase P: per-block precompute (identical across blocks) =================
  {
    float* s_mb = S+LT_AR;        // 3000: mk staged, then bar_b in place
    float* s_w  = S+LT_AR+3000;
    float* s_sw = S+LT_AR+3104;
    float* s_bw = S+LT_AR+3208;
    float* s_C  = S+LT_AR+3240;
    float* s_Hi = S+LT_AR+3340;
    float* s_G  = S+LT_AR+3440;
    float* s_T  = S+LT_AR+3540;
    float* s_gv = S+LT_AR+3640;
    float* s_Ht = S+LT_AR+3652;
    float* s_z  = S+LT_AR+3664;
    float* sm   = S+LT_SM;

    for (int i=tid;i<3000;i+=256) s_mb[i]=mk[i];
    for (int i=tid;i<100;i+=256){ float x=w[i]; s_w[i]=x; s_sw[i]=sqrtf(x); }
    __syncthreads();

    float av = s_w[lane] + ((lane<36)? s_w[lane+64] : 0.f);
    #pragma unroll
    for (int m=32;m;m>>=1) av += __shfl_xor(av,m);
    const float wsum = av;
    const float rws  = 1.0f/av;

    if (tid<30){      // b_w rows
      const float4* p=(const float4*)&s_mb[tid*100];
      const float4* q=(const float4*)&s_w[0];
      float acc=0;
      #pragma unroll 5
      for (int j=0;j<25;j++){ float4 x=p[j], yv=q[j];
        acc=fmaf(x.x,yv.x,acc); acc=fmaf(x.y,yv.y,acc);
        acc=fmaf(x.z,yv.z,acc); acc=fmaf(x.w,yv.w,acc); }
      s_bw[tid]=acc*rws;
    }
    __syncthreads();
    for (int i=tid;i<3000;i+=256){ int r=i/100, n=i-r*100; s_mb[i]=s_sw[n]*(s_mb[i]-s_bw[r]); }
    __syncthreads();
    if (tid<100){     // C = barB^T barB
      int k=tid/10, k2=tid-10*(tid/10);
      const float4* p1=(const float4*)&s_mb[k*300];
      const float4* p2=(const float4*)&s_mb[k2*300];
      float acc=0;
      #pragma unroll 5
      for (int j=0;j<75;j++){ float4 x=p1[j], yv=p2[j];
        acc=fmaf(x.x,yv.x,acc); acc=fmaf(x.y,yv.y,acc);
        acc=fmaf(x.z,yv.z,acc); acc=fmaf(x.w,yv.w,acc); }
      s_C[tid]=acc;
    }
    __syncthreads();
    if (tid<64){      // GJ inversion of 2(C+I), wave0 lanes 0..9 own rows
      float R[20];
      {
        int row=(tid<10)? tid : 0;
        #pragma unroll
        for (int c=0;c<10;c++) R[c]=2.0f*(s_C[row*10+c]+(c==row?1.0f:0.0f));
        #pragma unroll
        for (int c=0;c<10;c++) R[10+c]=(c==row)?1.0f:0.0f;
      }
      #pragma unroll
      for (int p=0;p<10;p++){
        float appv=__shfl(R[p],p);
        float ra=1.0f/appv;
        float fr=R[p];
        #pragma unroll
        for (int c=0;c<20;c++){
          float pc=__shfl(R[c],p)*ra;
          R[c]=(tid==p)? pc : fmaf(-fr,pc,R[c]);
        }
      }
      if (tid<10){
        float ht=0.f;
        #pragma unroll
        for (int c=0;c<10;c++){ s_Hi[tid*10+c]=R[10+c]; ht+=R[10+c]; }
        s_Ht[tid]=ht;
      }
    }
    __syncthreads();
    float dsum=0.f;
    #pragma unroll
    for (int k=0;k<10;k++) dsum+=s_Ht[k];
    const float rden=1.0f/dsum;
    if (tid<10) s_gv[tid]=s_Ht[tid]*rden;
    __syncthreads();
    if (tid<100){ int r=tid/10,c=tid-10*(tid/10); s_G[tid]=s_Hi[tid]-s_Ht[r]*s_Ht[c]*rden; }
    __syncthreads();
    if (tid<100){     // T = (C+I)G
      int r=tid/10,c=tid-10*(tid/10); float acc=0;
      #pragma unroll
      for (int j=0;j<10;j++) acc+=(s_C[r*10+j]+(r==j?1.0f:0.0f))*s_G[j*10+c];
      s_T[tid]=acc;
    }
    __syncthreads();
    if (tid<100){     // W = 4G(C+I)G - 4G ; emit G
      int r=tid/10,c=tid-10*(tid/10); float acc=0;
      #pragma unroll
      for (int j=0;j<10;j++) acc+=s_G[r*10+j]*s_T[j*10+c];
      sm[SM_W+tid]=4.0f*acc-4.0f*s_G[tid];
      sm[SM_G+tid]=s_G[tid];
    }
    if (tid<10){      // z = (C+I)g
      float acc=0;
      #pragma unroll
      for (int j=0;j<10;j++) acc+=(s_C[tid*10+j]+(tid==j?1.0f:0.0f))*s_gv[j];
      s_z[tid]=acc;
    }
    __syncthreads();
    if (tid<10){      // z2 = 2Gz - g
      float acc=0;
      #pragma unroll
      for (int j=0;j<10;j++) acc+=s_G[tid*10+j]*s_z[j];
      sm[SM_Z2+tid]=2.0f*acc-s_gv[tid];
    }
    if (tid==0){      // q00 = g^T C g + g.g
      float acc=0;
      #pragma unroll
      for (int r=0;r<10;r++){
        float rr=0;
        #pragma unroll
        for (int c=0;c<10;c++) rr+=s_C[r*10+c]*s_gv[c];
        acc+=s_gv[r]*rr+s_gv[r]*s_gv[r];
      }
      sm[SM_WSUM]=wsum; sm[SM_RWS]=rws; sm[SM_Q00]=acc; sm[3]=0.f;
    }
    // cT[c][l][u] = barb[l][n]*sw[n], n=4c+u  (transposed: consecutive-lane b128)
    for (int i=tid;i<3000;i+=256){
      int l=i/100, n=i-100*l;
      S[LT_CT + ((n>>2)*32 + l)*4 + (n&3)] = s_mb[i]*s_sw[n];
    }
    for (int i=tid;i<200;i+=256){ int c=i>>3, r=i&7; S[LT_CT+(c*32+30)*4+r]=0.f; } // rows 30,31
    for (int i=tid;i<100;i+=256) S[LT_WT+i]=s_w[i];
    if (tid<30){      // bs[row] = sum_n barb*sw
      const float4* p=(const float4*)&s_mb[tid*100];
      const float4* q=(const float4*)&s_sw[0];
      float acc=0;
      #pragma unroll 5
      for (int j=0;j<25;j++){ float4 x=p[j], yv=q[j];
        acc=fmaf(x.x,yv.x,acc); acc=fmaf(x.y,yv.y,acc);
        acc=fmaf(x.z,yv.z,acc); acc=fmaf(x.w,yv.w,acc); }
      sm[SM_BS+tid]=acc;
    }
    if (tid<2)  sm[SM_BS+30+tid]=0.f;
    if (tid<10) sm[SM_GV+tid]=s_gv[tid];
    if (tid<30) sm[SM_BW+tid]=s_bw[tid];
    __syncthreads();   // Phase P done; arena reusable
  }

  const float* sm = S+LT_SM;
  float* yS = S+LT_AR+A_YS;
  float* sF = S+LT_AR+A_SF;
  float* sQ = S+LT_AR+A_QL;
  float* sX = S+LT_AR+A_AX;

  // ---- A1: stage this block's 8 y items into LDS (coalesced linear f4 copy) ----
  {
    const float4* yg = (const float4*)(y + (size_t)blockIdx.x*2400);
    #pragma unroll
    for (int r=0;r<3;r++){
      int f = tid + 256*r;
      if (f<600){
        int it2=f/75, rem=f-75*it2;
        ((float4*)&yS[it2*304])[rem] = yg[f];
      }
    }
  }
  __syncthreads();

  const float* yb = &yS[item*304];

  // ---- A2: stats (n-split over the item's 32 lanes) ----
  float swy0=0,swy1=0,swy2=0,s00=0,s01=0,s02=0,s11=0,s12=0,s22=0;
  #pragma unroll
  for (int m=0;m<3;m++){
    int n=sub+32*m;
    float y0=yb[n], y1=yb[100+n], y2=yb[200+n];
    float wn=S[LT_WT+n];
    float wy0=wn*y0,wy1=wn*y1,wy2=wn*y2;
    swy0+=wy0;swy1+=wy1;swy2+=wy2;
    s00+=wy0*y0;s01+=wy0*y1;s02+=wy0*y2;s11+=wy1*y1;s12+=wy1*y2;s22+=wy2*y2;
  }
  if (sub<4){
    int n=96+sub;
    float y0=yb[n], y1=yb[100+n], y2=yb[200+n];
    float wn=S[LT_WT+n];
    float wy0=wn*y0,wy1=wn*y1,wy2=wn*y2;
    swy0+=wy0;swy1+=wy1;swy2+=wy2;
    s00+=wy0*y0;s01+=wy0*y1;s02+=wy0*y2;s11+=wy1*y1;s12+=wy1*y2;s22+=wy2*y2;
  }
  swy0=gsum32(swy0); swy1=gsum32(swy1); swy2=gsum32(swy2);
  s00=gsum32(s00); s01=gsum32(s01); s02=gsum32(s02);
  s11=gsum32(s11); s12=gsum32(s12); s22=gsum32(s22);

  const float wsum=sm[SM_WSUM], rws=sm[SM_RWS];
  const float yw0=swy0*rws, yw1=swy1*rws, yw2=swy2*rws;

  // ---- A3: F element-split — lane sub<30 owns coef row sub (3 scalar accs) ----
  {
    float a0=0,a1=0,a2=0;
    #pragma unroll 5
    for (int c=0;c<25;c++){
      float4 cf = *(const float4*)&S[LT_CT+(c*32+sub)*4];   // consecutive-lane b128
      float4 ya = *(const float4*)&yb[4*c];                 // 32-lane broadcast
      float4 yB = *(const float4*)&yb[100+4*c];
      float4 yc = *(const float4*)&yb[200+4*c];
      a0=fmaf(cf.x,ya.x,a0); a0=fmaf(cf.y,ya.y,a0); a0=fmaf(cf.z,ya.z,a0); a0=fmaf(cf.w,ya.w,a0);
      a1=fmaf(cf.x,yB.x,a1); a1=fmaf(cf.y,yB.y,a1); a1=fmaf(cf.z,yB.z,a1); a1=fmaf(cf.w,yB.w,a1);
      a2=fmaf(cf.x,yc.x,a2); a2=fmaf(cf.y,yc.y,a2); a2=fmaf(cf.z,yc.z,a2); a2=fmaf(cf.w,yc.w,a2);
    }
    if (sub<30){
      float bsv=sm[SM_BS+sub];
      a0-=yw0*bsv; a1-=yw1*bsv; a2-=yw2*bsv;
      sF[item*97+sub*3+0]=a0; sF[item*97+sub*3+1]=a1; sF[item*97+sub*3+2]=a2;
    }
    if (sub==0){
      float* ax=&sX[item*16];
      ax[0]=yw0; ax[1]=yw1; ax[2]=yw2;
      ax[3+0]=s00-wsum*yw0*yw0;
      ax[3+4]=s11-wsum*yw1*yw1;
      ax[3+8]=s22-wsum*yw2*yw2;
      float g01=s01-wsum*yw0*yw1, g02=s02-wsum*yw0*yw2, g12=s12-wsum*yw1*yw2;
      ax[3+1]=g01; ax[3+3]=g01;
      ax[3+2]=g02; ax[3+6]=g02;
      ax[3+5]=g12; ax[3+7]=g12;
    }
  }
  __syncthreads();

  // ---- A4: Q assembly — 72 column tasks + 8 q00 writes ----
  if (tid<72){
    int it2=tid/9, mp=tid-9*(tid/9);
    float fcol[10], t2[10];
    #pragma unroll
    for (int k=0;k<10;k++) fcol[k]=sF[it2*97+k*9+mp];
    #pragma unroll
    for (int k=0;k<10;k++){
      float acc=0;
      #pragma unroll
      for (int k2=0;k2<10;k2++) acc+=sm[SM_W+k*10+k2]*fcol[k2];
      t2[k]=acc;
    }
    float he=0;
    #pragma unroll
    for (int k=0;k<10;k++) he+=sm[SM_Z2+k]*fcol[k];
    sQ[it2*57 + 1+mp]=he;
    #pragma unroll 1
    for (int m=0;m<=mp;m++){
      float gd=sX[it2*16+3+(m%3)*3+(mp%3)];
      float acc=((m/3)==(mp/3))? gd : 0.f;
      #pragma unroll
      for (int k=0;k<10;k++) acc+=sF[it2*97+k*9+m]*t2[k];
      int p=1+m, q=1+mp;
      sQ[it2*57 + p*10-((p*(p+1))>>1)+q]=acc;
    }
  }
  if (tid>=72 && tid<80) sQ[(tid-72)*57]=sm[SM_Q00];
  __syncthreads();

  // ================= Eigen + epilogue: one item per lane (tid<8) — R8-proven tail =================
  if (tid<8){
    const int it2=tid;
    const int gb2=blockIdx.x*8+it2;
    float A[55];
    #pragma unroll
    for (int e=0;e<55;e++) A[e]=sQ[it2*57+e];
    float dd[10], ee[9];
    #pragma unroll
    for (int k=0;k<8;k++){
      float nrm2=0.f;
      #pragma unroll
      for (int i=1;i<10;i++){ if (i<k+1) continue; float xi=A[SIDX(i,k)]; nrm2=fmaf(xi,xi,nrm2); }
      float x0=A[SIDX(k+1,k)];
      float nr=sqrtf(nrm2);
      float alpha=-copysignf(nr,x0);
      bool ok=nrm2>1e-30f;
      float v1=x0-alpha;
      float vtv=-2.0f*alpha*v1;
      float bh=ok?2.0f*__builtin_amdgcn_rcpf(vtv):0.f;
      ee[k]=ok?alpha:x0;
      float vv[10];
      #pragma unroll
      for (int i=0;i<10;i++) vv[i]=(i<k+1)?0.f:((i==k+1)?v1:A[SIDX(i,k)]);
      float p[10];
      #pragma unroll
      for (int i=0;i<10;i++){
        if (i<k+1){ p[i]=0.f; continue; }
        float acc=0;
        #pragma unroll
        for (int j=1;j<10;j++){ if (j<k+1) continue; acc+=A[SIDX(i,j)]*vv[j]; }
        p[i]=bh*acc;
      }
      float Kc=0.f;
      #pragma unroll
      for (int i=1;i<10;i++){ if (i<k+1) continue; Kc=fmaf(vv[i],p[i],Kc); }
      Kc*=0.5f*bh;
      float wv[10];
      #pragma unroll
      for (int i=0;i<10;i++) wv[i]=p[i]-Kc*vv[i];
      #pragma unroll
      for (int i=1;i<10;i++){
        if (i<k+1) continue;
        #pragma unroll
        for (int j=1;j<10;j++){
          if (j<i) continue;
          A[TRI(i,j)]-=vv[i]*wv[j]+wv[i]*vv[j];
        }
      }
    }
    ee[8]=A[TRI(8,9)];
    #pragma unroll
    for (int i=0;i<10;i++) dd[i]=A[TRI(i,i)];
    float esq[9];
    #pragma unroll
    for (int i=0;i<9;i++) esq[i]=ee[i]*ee[i];

    float scaleT=0.f, lo=1e30f, hi=1e30f;
    #pragma unroll
    for (int i=0;i<10;i++){
      float r=((i>0)?fabsf(ee[i-1]):0.f)+((i<9)?fabsf(ee[i]):0.f);
      scaleT=fmaxf(scaleT,fabsf(dd[i])+r);
      lo=fminf(lo,dd[i]-r);
      hi=fminf(hi,dd[i]);
    }
    hi+=1e-6f*scaleT+1e-30f;
    const float pm=1e-12f*scaleT+1e-37f;
    #pragma unroll 1
    for (int it=0;it<16;++it){
      float mid=0.5f*(lo+hi);
      float q=dd[0]-mid;
      q=(fabsf(q)<pm)?((q<0.f)?-pm:pm):q;
      int cnt=(q<0.f);
      #pragma unroll
      for (int i=1;i<10;i++){
        q=dd[i]-mid-esq[i-1]*__builtin_amdgcn_rcpf(q);
        q=(fabsf(q)<pm)?((q<0.f)?-pm:pm):q;
        cnt+=(q<0.f);
      }
      bool any=cnt>0;
      hi=any?mid:hi;
      lo=any?lo:mid;
    }
    const float sigma=lo-1e-5f*scaleT-1e-30f;   // cnt(sigma)==0; margin caps amplification
    const float pmL=1e-8f*scaleT+1e-37f;

    float Lc[55], rd[10];
    #pragma unroll
    for (int i=0;i<10;i++){
      #pragma unroll
      for (int j=0;j<10;j++){
        if (j>i) continue;
        float a=sQ[it2*57+SIDX(j,i)]-((i==j)?sigma:0.f);
        #pragma unroll
        for (int t2=0;t2<9;t2++){
          if (t2>=j) continue;
          a-=Lc[LTRI(i,t2)]*Lc[LTRI(j,t2)];
        }
        if (j<i) Lc[LTRI(i,j)]=a*rd[j];
        else { a=fmaxf(a,pmL); rd[i]=rsqrtf(a); Lc[LTRI(i,i)]=a*rd[i]; }
      }
    }
    float xv[10];
    #pragma unroll
    for (int i=0;i<10;i++) xv[i]=1.f;
    #pragma unroll 1
    for (int itr=0;itr<3;++itr){
      #pragma unroll
      for (int i=0;i<10;i++){
        float acc=xv[i];
        #pragma unroll
        for (int j=0;j<9;j++){ if (j>=i) continue; acc-=Lc[LTRI(i,j)]*xv[j]; }
        acc*=rd[i];
        xv[i]=fminf(fmaxf(acc,-1e15f),1e15f);
      }
      #pragma unroll
      for (int i=9;i>=0;i--){
        float acc=xv[i];
        #pragma unroll
        for (int j=9;j>0;j--){ if (j<=i) continue; acc-=Lc[LTRI(j,i)]*xv[j]; }
        acc*=rd[i];
        xv[i]=fminf(fmaxf(acc,-1e15f),1e15f);
      }
      float nn=0.f;
      #pragma unroll
      for (int i=0;i<10;i++) nn=fmaf(xv[i],xv[i],nn);
      nn=fmaxf(nn,1e-30f);
      float sc2=rsqrtf(nn);
      #pragma unroll
      for (int i=0;i<10;i++) xv[i]*=sc2;
    }
    float r0=1.0f/xv[0];
    float vn[10];
    vn[0]=1.f;
    #pragma unroll
    for (int m=1;m<10;m++) vn[m]=xv[m]*r0;

    // epilogue
    float dv[10];
    #pragma unroll
    for (int k=0;k<10;k++){
      float acc=0;
      #pragma unroll
      for (int m=0;m<9;m++) acc+=vn[1+m]*sF[it2*97+k*9+m];
      dv[k]=acc;
    }
    float cv[10];
    #pragma unroll
    for (int k=0;k<10;k++){
      float acc=0;
      #pragma unroll
      for (int k2=0;k2<10;k2++) acc+=sm[SM_G+k*10+k2]*dv[k2];
      cv[k]=2.0f*acc+sm[SM_GV+k];
    }
    float e0=0,e1=0,e2=0;
    #pragma unroll
    for (int k=0;k<10;k++){
      e0+=sm[SM_BW+k*3+0]*cv[k];
      e1+=sm[SM_BW+k*3+1]*cv[k];
      e2+=sm[SM_BW+k*3+2]*cv[k];
    }
    float ywa=sX[it2*16+0], ywb=sX[it2*16+1], ywc=sX[it2*16+2];
    #pragma unroll
    for (int i=0;i<3;i++)
      #pragma unroll
      for (int j=0;j<3;j++)
        out[gb2*9+i*3+j]=vn[1+3*j+i];
    out[73728+gb2*3+0]=ywa-(vn[1]*e0+vn[4]*e1+vn[7]*e2);
    out[73728+gb2*3+1]=ywb-(vn[2]*e0+vn[5]*e1+vn[8]*e2);
    out[73728+gb2*3+2]=ywc-(vn[3]*e0+vn[6]*e1+vn[9]*e2);
    #pragma unroll
    for (int k=0;k<10;k++)
      out[98304+gb2*10+k]=cv[k];
  }
}

extern "C" void kernel_launch(void* const* d_in, const int* in_sizes, int n_in,
                              void* d_out, int out_size, void* d_ws, size_t ws_size,
                              hipStream_t stream) {
  const float* y  = (const float*)d_in[0];   // (8192,3,100)
  const float* w  = (const float*)d_in[1];   // (100,1)
  const float* mk = (const float*)d_in[2];   // (10,3,100)
  float* out = (float*)d_out;                // R(8192*9) | t(8192*3) | c(8192*10)
  pace_fused<<<1024, 256, 0, stream>>>(y, w, mk, out);
}

// Round 13
// 99.910 us; speedup vs baseline: 1.1295x; 1.1295x over previous
//
#include <hip/hip_runtime.h>
#include <math.h>

// ---------------- persistent LDS layout (floats) ----------------
#define LT_CT 0        // cT[25][32][4]: cT[c][l][u] = w[n]*mk[l][n], n=4c+u; rows 30/31 zero
#define LT_WT 3200     // w[100] + pad
#define LT_SM 3304     // sm[292]
#define LT_AR 3600     // union arena (7584 floats)
#define LT_TOT 11184   // 44736 B

#define SM_WSUM 0
#define SM_RWS  1
#define SM_Q00  2
#define SM_Z2   4
#define SM_W    48
#define SM_G    148
#define SM_GV   248
#define SM_BW   260    // 32 slots (30 used, 30/31 zeroed)

// arena phase-A offsets (relative to LT_AR)
#define A_YS 0         // [16][304]  staged y
#define A_SF 4864      // [16][97]   centered F (stride 97: conflict-free)
#define A_QL 6416      // [16][57]   Q upper-tri
#define A_AX 7328      // [16][16]   yw[3] @0, G3[9] @3

__host__ __device__ constexpr int TRI(int p,int q){ return p*10-(p*(p+1))/2+q; } // p<=q
__host__ __device__ constexpr int SIDX(int a,int b){ return (a<=b)?TRI(a,b):TRI(b,a); }
__host__ __device__ constexpr int LTRI(int i,int j){ return i*(i+1)/2+j; }       // j<=i

template<int CTRL>
__device__ __forceinline__ float dpp_add(float v){
  int s = __builtin_amdgcn_mov_dpp(__float_as_int(v), CTRL, 0xF, 0xF, true);
  return v + __int_as_float(s);
}
// 16-lane group sum (DPP row = 16 lanes)
__device__ __forceinline__ float gsum16(float v){
  v = dpp_add<0xB1>(v);    // quad xor1
  v = dpp_add<0x4E>(v);    // quad xor2
  v = dpp_add<0x141>(v);   // row_half_mirror
  v = dpp_add<0x140>(v);   // row_mirror
  return v;
}

__global__ __launch_bounds__(256,2) void pace_fused(const float* __restrict__ y,
                                                    const float* __restrict__ w,
                                                    const float* __restrict__ mk,
                                                    float* __restrict__ out){
  __shared__ __attribute__((aligned(16))) float S[LT_TOT];
  const int tid  = threadIdx.x;
  const int lane = tid & 63;
  const int sub  = tid & 15;      // lane within item
  const int item = tid >> 4;      // 0..15

  // ================= Phase P: per-block precompute (cT = w*mk; C keypoint-level) =================
  {
    float* s_mb = S+LT_AR;          // 3000: raw mk
    float* s_w  = S+LT_AR+3000;     // 104
    float* s_M1 = S+LT_AR+3104;     // 32 : M1[l] = sum_n w*mk[l,n]  (l = 3k+j, 30 rows)
    float* s_C  = S+LT_AR+3136;     // 100: keypoint-level C
    float* s_Hi = S+LT_AR+3236;
    float* s_G  = S+LT_AR+3336;
    float* s_T  = S+LT_AR+3436;
    float* s_gv = S+LT_AR+3536;
    float* s_Ht = S+LT_AR+3548;
    float* s_z  = S+LT_AR+3560;
    float* sm   = S+LT_SM;

    for (int i=tid;i<3000;i+=256) s_mb[i]=mk[i];
    for (int i=tid;i<100;i+=256){ float x=w[i]; s_w[i]=x; S[LT_WT+i]=x; }
    __syncthreads();

    // wsum butterfly (all threads hold wsum/rws)
    float av = s_w[lane] + ((lane<36)? s_w[lane+64] : 0.f);
    #pragma unroll
    for (int m=32;m;m>>=1) av += __shfl_xor(av,m);
    const float wsum = av;
    const float rws  = 1.0f/av;

    // phase 2: cT = w*mk (all threads); M1 rows (tid<30); zero pads
    for (int i=tid;i<3000;i+=256){
      int l=i/100, n=i-100*l;
      S[LT_CT + ((n>>2)*32 + l)*4 + (n&3)] = s_w[n]*s_mb[i];
    }
    for (int i=tid;i<200;i+=256){ int c=i>>3, r=i&7; S[LT_CT+(c*32+30)*4+r]=0.f; } // rows 30,31
    if (tid<30){
      const float4* p=(const float4*)&s_mb[tid*100];
      const float4* q=(const float4*)&s_w[0];
      float acc=0;
      #pragma unroll 5
      for (int j=0;j<25;j++){ float4 x=p[j], yv=q[j];
        acc=fmaf(x.x,yv.x,acc); acc=fmaf(x.y,yv.y,acc);
        acc=fmaf(x.z,yv.z,acc); acc=fmaf(x.w,yv.w,acc); }
      s_M1[tid]=acc;
    }
    __syncthreads();

    // phase 3: KEYPOINT-level C (tid<100): sum over 3 axes of (cT row 3k+j)·(mk row 3k2+j)
    //          minus M1-pair correction per axis.  bw -> sm (tid 128..157); pads.
    if (tid<100){
      int k=tid/10, k2=tid-10*(tid/10);
      float acc=0;
      #pragma unroll
      for (int j=0;j<3;j++){
        int la=3*k+j, lb=3*k2+j;
        const float4* p2=(const float4*)&s_mb[lb*100];
        float part=0;
        #pragma unroll 5
        for (int c=0;c<25;c++){
          float4 a=*(const float4*)&S[LT_CT+(c*32+la)*4];
          float4 b=p2[c];
          part=fmaf(a.x,b.x,part); part=fmaf(a.y,b.y,part);
          part=fmaf(a.z,b.z,part); part=fmaf(a.w,b.w,part);
        }
        acc += part - s_M1[la]*s_M1[lb]*rws;
      }
      s_C[tid]=acc;
    }
    if (tid>=128 && tid<158) sm[SM_BW+(tid-128)] = s_M1[tid-128]*rws;
    if (tid>=158 && tid<160) sm[SM_BW+30+(tid-158)] = 0.f;
    __syncthreads();

    // phase 4: GJ inversion of 2(C+I), wave0 lanes 0..9 own rows (R10-proven, s_C based)
    if (tid<64){
      float R[20];
      {
        int row=(tid<10)? tid : 0;
        #pragma unroll
        for (int c=0;c<10;c++) R[c]=2.0f*(s_C[row*10+c]+(c==row?1.0f:0.0f));
        #pragma unroll
        for (int c=0;c<10;c++) R[10+c]=(c==row)?1.0f:0.0f;
      }
      #pragma unroll
      for (int p=0;p<10;p++){
        float appv=__shfl(R[p],p);
        float ra=1.0f/appv;
        float fr=R[p];
        #pragma unroll
        for (int c=0;c<20;c++){
          float pc=__shfl(R[c],p)*ra;
          R[c]=(tid==p)? pc : fmaf(-fr,pc,R[c]);
        }
      }
      if (tid<10){
        float ht=0.f;
        #pragma unroll
        for (int c=0;c<10;c++){ s_Hi[tid*10+c]=R[10+c]; ht+=R[10+c]; }
        s_Ht[tid]=ht;
      }
    }
    __syncthreads();
    float dsum=0.f;
    #pragma unroll
    for (int k=0;k<10;k++) dsum+=s_Ht[k];
    const float rden=1.0f/dsum;
    if (tid<10) s_gv[tid]=s_Ht[tid]*rden;
    __syncthreads();
    if (tid<100){ int r=tid/10,c=tid-10*(tid/10); s_G[tid]=s_Hi[tid]-s_Ht[r]*s_Ht[c]*rden; }
    __syncthreads();
    if (tid<100){     // T = (C+I)G  (s_C based, R10-proven)
      int r=tid/10,c=tid-10*(tid/10); float acc=0;
      #pragma unroll
      for (int j=0;j<10;j++) acc+=(s_C[r*10+j]+(r==j?1.0f:0.0f))*s_G[j*10+c];
      s_T[tid]=acc;
    }
    __syncthreads();
    if (tid<100){     // W = 4G(C+I)G - 4G ; emit G
      int r=tid/10,c=tid-10*(tid/10); float acc=0;
      #pragma unroll
      for (int j=0;j<10;j++) acc+=s_G[r*10+j]*s_T[j*10+c];
      sm[SM_W+tid]=4.0f*acc-4.0f*s_G[tid];
      sm[SM_G+tid]=s_G[tid];
    }
    if (tid<10){      // z = (C+I)g
      float acc=0;
      #pragma unroll
      for (int j=0;j<10;j++) acc+=(s_C[tid*10+j]+(tid==j?1.0f:0.0f))*s_gv[j];
      s_z[tid]=acc;
    }
    __syncthreads();
    if (tid<10){      // z2 = 2Gz - g
      float acc=0;
      #pragma unroll
      for (int j=0;j<10;j++) acc+=s_G[tid*10+j]*s_z[j];
      sm[SM_Z2+tid]=2.0f*acc-s_gv[tid];
    }
    if (tid==0){      // q00 = g^T C g + g.g
      float acc=0;
      #pragma unroll
      for (int r=0;r<10;r++){
        float rr=0;
        #pragma unroll
        for (int c=0;c<10;c++) rr+=s_C[r*10+c]*s_gv[c];
        acc+=s_gv[r]*rr+s_gv[r]*s_gv[r];
      }
      sm[SM_WSUM]=wsum; sm[SM_RWS]=rws; sm[SM_Q00]=acc; sm[3]=0.f;
    }
    if (tid<10) sm[SM_GV+tid]=s_gv[tid];
    __syncthreads();   // Phase P done; arena reusable
  }

  const float* sm = S+LT_SM;
  float* yS = S+LT_AR+A_YS;
  float* sF = S+LT_AR+A_SF;
  float* sQ = S+LT_AR+A_QL;
  float* sX = S+LT_AR+A_AX;

  // ---- A1: stage this block's 16 y items into LDS (coalesced linear f4 copy) ----
  {
    const float4* yg = (const float4*)(y + (size_t)blockIdx.x*4800);
    #pragma unroll
    for (int r=0;r<5;r++){
      int f = tid + 256*r;
      if (f<1200){
        int it2=f/75, rem=f-75*it2;
        ((float4*)&yS[it2*304])[rem] = yg[f];
      }
    }
  }
  __syncthreads();

  const float* yb = &yS[item*304];

  // ---- A2: stats (n-split over the item's 16 lanes) ----
  float swy0=0,swy1=0,swy2=0,s00=0,s01=0,s02=0,s11=0,s12=0,s22=0;
  #pragma unroll
  for (int m=0;m<6;m++){
    int n=sub+16*m;
    float y0=yb[n], y1=yb[100+n], y2=yb[200+n];
    float wn=S[LT_WT+n];
    float wy0=wn*y0,wy1=wn*y1,wy2=wn*y2;
    swy0+=wy0;swy1+=wy1;swy2+=wy2;
    s00+=wy0*y0;s01+=wy0*y1;s02+=wy0*y2;s11+=wy1*y1;s12+=wy1*y2;s22+=wy2*y2;
  }
  if (sub<4){
    int n=96+sub;
    float y0=yb[n], y1=yb[100+n], y2=yb[200+n];
    float wn=S[LT_WT+n];
    float wy0=wn*y0,wy1=wn*y1,wy2=wn*y2;
    swy0+=wy0;swy1+=wy1;swy2+=wy2;
    s00+=wy0*y0;s01+=wy0*y1;s02+=wy0*y2;s11+=wy1*y1;s12+=wy1*y2;s22+=wy2*y2;
  }
  swy0=gsum16(swy0); swy1=gsum16(swy1); swy2=gsum16(swy2);
  s00=gsum16(s00); s01=gsum16(s01); s02=gsum16(s02);
  s11=gsum16(s11); s12=gsum16(s12); s22=gsum16(s22);

  const float wsum=sm[SM_WSUM], rws=sm[SM_RWS];
  const float yw0=swy0*rws, yw1=swy1*rws, yw2=swy2*rws;

  // ---- A3: F element-split — lane owns cT rows sub, sub+16; centering via bw*swy ----
  {
    float a0=0,a1=0,a2=0,b0=0,b1=0,b2=0;
    #pragma unroll 5
    for (int c=0;c<25;c++){
      float4 cfA = *(const float4*)&S[LT_CT+(c*32+sub)*4];
      float4 cfB = *(const float4*)&S[LT_CT+(c*32+sub+16)*4];
      float4 ya  = *(const float4*)&yb[4*c];
      float4 yB  = *(const float4*)&yb[100+4*c];
      float4 yc  = *(const float4*)&yb[200+4*c];
      a0=fmaf(cfA.x,ya.x,a0); a0=fmaf(cfA.y,ya.y,a0); a0=fmaf(cfA.z,ya.z,a0); a0=fmaf(cfA.w,ya.w,a0);
      a1=fmaf(cfA.x,yB.x,a1); a1=fmaf(cfA.y,yB.y,a1); a1=fmaf(cfA.z,yB.z,a1); a1=fmaf(cfA.w,yB.w,a1);
      a2=fmaf(cfA.x,yc.x,a2); a2=fmaf(cfA.y,yc.y,a2); a2=fmaf(cfA.z,yc.z,a2); a2=fmaf(cfA.w,yc.w,a2);
      b0=fmaf(cfB.x,ya.x,b0); b0=fmaf(cfB.y,ya.y,b0); b0=fmaf(cfB.z,ya.z,b0); b0=fmaf(cfB.w,ya.w,b0);
      b1=fmaf(cfB.x,yB.x,b1); b1=fmaf(cfB.y,yB.y,b1); b1=fmaf(cfB.z,yB.z,b1); b1=fmaf(cfB.w,yB.w,b1);
      b2=fmaf(cfB.x,yc.x,b2); b2=fmaf(cfB.y,yc.y,b2); b2=fmaf(cfB.z,yc.z,b2); b2=fmaf(cfB.w,yc.w,b2);
    }
    float bwA=sm[SM_BW+sub], bwB=sm[SM_BW+sub+16];
    a0-=bwA*swy0; a1-=bwA*swy1; a2-=bwA*swy2;
    b0-=bwB*swy0; b1-=bwB*swy1; b2-=bwB*swy2;
    sF[item*97+sub*3+0]=a0; sF[item*97+sub*3+1]=a1; sF[item*97+sub*3+2]=a2;
    sF[item*97+48+sub*3+0]=b0; sF[item*97+48+sub*3+1]=b1; sF[item*97+48+sub*3+2]=b2;
    if (sub==0){
      float* ax=&sX[item*16];
      ax[0]=yw0; ax[1]=yw1; ax[2]=yw2;
      ax[3+0]=s00-wsum*yw0*yw0;
      ax[3+4]=s11-wsum*yw1*yw1;
      ax[3+8]=s22-wsum*yw2*yw2;
      float g01=s01-wsum*yw0*yw1, g02=s02-wsum*yw0*yw2, g12=s12-wsum*yw1*yw2;
      ax[3+1]=g01; ax[3+3]=g01;
      ax[3+2]=g02; ax[3+6]=g02;
      ax[3+5]=g12; ax[3+7]=g12;
    }
  }
  __syncthreads();

  // ---- A4: Q assembly — 144 column tasks + 16 q00 writes ----
  if (tid<144){
    int it2=tid/9, mp=tid-9*(tid/9);
    float fcol[10], t2[10];
    #pragma unroll
    for (int k=0;k<10;k++) fcol[k]=sF[it2*97+k*9+mp];
    #pragma unroll
    for (int k=0;k<10;k++){
      float acc=0;
      #pragma unroll
      for (int k2=0;k2<10;k2++) acc+=sm[SM_W+k*10+k2]*fcol[k2];
      t2[k]=acc;
    }
    float he=0;
    #pragma unroll
    for (int k=0;k<10;k++) he+=sm[SM_Z2+k]*fcol[k];
    sQ[it2*57 + 1+mp]=he;
    #pragma unroll 1
    for (int m=0;m<=mp;m++){
      float gd=sX[it2*16+3+(m%3)*3+(mp%3)];
      float acc=((m/3)==(mp/3))? gd : 0.f;
      #pragma unroll
      for (int k=0;k<10;k++) acc+=sF[it2*97+k*9+m]*t2[k];
      int p=1+m, q=1+mp;
      sQ[it2*57 + p*10-((p*(p+1))>>1)+q]=acc;
    }
  }
  if (tid>=144 && tid<160) sQ[(tid-144)*57]=sm[SM_Q00];
  __syncthreads();

  // ================= Eigen + epilogue: one item per lane (tid<16) — proven tail =================
  if (tid<16){
    const int it2=tid;
    const int gb2=blockIdx.x*16+it2;
    float A[55];
    #pragma unroll
    for (int e=0;e<55;e++) A[e]=sQ[it2*57+e];
    float dd[10], ee[9];
    #pragma unroll
    for (int k=0;k<8;k++){
      float nrm2=0.f;
      #pragma unroll
      for (int i=1;i<10;i++){ if (i<k+1) continue; float xi=A[SIDX(i,k)]; nrm2=fmaf(xi,xi,nrm2); }
      float x0=A[SIDX(k+1,k)];
      float nr=sqrtf(nrm2);
      float alpha=-copysignf(nr,x0);
      bool ok=nrm2>1e-30f;
      float v1=x0-alpha;
      float vtv=-2.0f*alpha*v1;
      float bh=ok?2.0f*__builtin_amdgcn_rcpf(vtv):0.f;
      ee[k]=ok?alpha:x0;
      float vv[10];
      #pragma unroll
      for (int i=0;i<10;i++) vv[i]=(i<k+1)?0.f:((i==k+1)?v1:A[SIDX(i,k)]);
      float p[10];
      #pragma unroll
      for (int i=0;i<10;i++){
        if (i<k+1){ p[i]=0.f; continue; }
        float acc=0;
        #pragma unroll
        for (int j=1;j<10;j++){ if (j<k+1) continue; acc+=A[SIDX(i,j)]*vv[j]; }
        p[i]=bh*acc;
      }
      float Kc=0.f;
      #pragma unroll
      for (int i=1;i<10;i++){ if (i<k+1) continue; Kc=fmaf(vv[i],p[i],Kc); }
      Kc*=0.5f*bh;
      float wv[10];
      #pragma unroll
      for (int i=0;i<10;i++) wv[i]=p[i]-Kc*vv[i];
      #pragma unroll
      for (int i=1;i<10;i++){
        if (i<k+1) continue;
        #pragma unroll
        for (int j=1;j<10;j++){
          if (j<i) continue;
          A[TRI(i,j)]-=vv[i]*wv[j]+wv[i]*vv[j];
        }
      }
    }
    ee[8]=A[TRI(8,9)];
    #pragma unroll
    for (int i=0;i<10;i++) dd[i]=A[TRI(i,i)];
    float esq[9];
    #pragma unroll
    for (int i=0;i<9;i++) esq[i]=ee[i]*ee[i];

    float scaleT=0.f, lo=1e30f, hi=1e30f;
    #pragma unroll
    for (int i=0;i<10;i++){
      float r=((i>0)?fabsf(ee[i-1]):0.f)+((i<9)?fabsf(ee[i]):0.f);
      scaleT=fmaxf(scaleT,fabsf(dd[i])+r);
      lo=fminf(lo,dd[i]-r);
      hi=fminf(hi,dd[i]);
    }
    hi+=1e-6f*scaleT+1e-30f;
    const float pm=1e-12f*scaleT+1e-37f;
    #pragma unroll 1
    for (int it=0;it<16;++it){
      float mid=0.5f*(lo+hi);
      float q=dd[0]-mid;
      q=(fabsf(q)<pm)?((q<0.f)?-pm:pm):q;
      int cnt=(q<0.f);
      #pragma unroll
      for (int i=1;i<10;i++){
        q=dd[i]-mid-esq[i-1]*__builtin_amdgcn_rcpf(q);
        q=(fabsf(q)<pm)?((q<0.f)?-pm:pm):q;
        cnt+=(q<0.f);
      }
      bool any=cnt>0;
      hi=any?mid:hi;
      lo=any?lo:mid;
    }
    const float sigma=lo-1e-5f*scaleT-1e-30f;   // cnt(sigma)==0; margin caps amplification
    const float pmL=1e-8f*scaleT+1e-37f;

    float Lc[55], rd[10];
    #pragma unroll
    for (int i=0;i<10;i++){
      #pragma unroll
      for (int j=0;j<10;j++){
        if (j>i) continue;
        float a=sQ[it2*57+SIDX(j,i)]-((i==j)?sigma:0.f);
        #pragma unroll
        for (int t2=0;t2<9;t2++){
          if (t2>=j) continue;
          a-=Lc[LTRI(i,t2)]*Lc[LTRI(j,t2)];
        }
        if (j<i) Lc[LTRI(i,j)]=a*rd[j];
        else { a=fmaxf(a,pmL); rd[i]=rsqrtf(a); Lc[LTRI(i,i)]=a*rd[i]; }
      }
    }
    float xv[10];
    #pragma unroll
    for (int i=0;i<10;i++) xv[i]=1.f;
    #pragma unroll 1
    for (int itr=0;itr<3;++itr){
      #pragma unroll
      for (int i=0;i<10;i++){
        float acc=xv[i];
        #pragma unroll
        for (int j=0;j<9;j++){ if (j>=i) continue; acc-=Lc[LTRI(i,j)]*xv[j]; }
        acc*=rd[i];
        xv[i]=fminf(fmaxf(acc,-1e15f),1e15f);
      }
      #pragma unroll
      for (int i=9;i>=0;i--){
        float acc=xv[i];
        #pragma unroll
        for (int j=9;j>0;j--){ if (j<=i) continue; acc-=Lc[LTRI(j,i)]*xv[j]; }
        acc*=rd[i];
        xv[i]=fminf(fmaxf(acc,-1e15f),1e15f);
      }
      float nn=0.f;
      #pragma unroll
      for (int i=0;i<10;i++) nn=fmaf(xv[i],xv[i],nn);
      nn=fmaxf(nn,1e-30f);
      float sc2=rsqrtf(nn);
      #pragma unroll
      for (int i=0;i<10;i++) xv[i]*=sc2;
    }
    float r0=1.0f/xv[0];
    float vn[10];
    vn[0]=1.f;
    #pragma unroll
    for (int m=1;m<10;m++) vn[m]=xv[m]*r0;

    // epilogue
    float dv[10];
    #pragma unroll
    for (int k=0;k<10;k++){
      float acc=0;
      #pragma unroll
      for (int m=0;m<9;m++) acc+=vn[1+m]*sF[it2*97+k*9+m];
      dv[k]=acc;
    }
    float cv[10];
    #pragma unroll
    for (int k=0;k<10;k++){
      float acc=0;
      #pragma unroll
      for (int k2=0;k2<10;k2++) acc+=sm[SM_G+k*10+k2]*dv[k2];
      cv[k]=2.0f*acc+sm[SM_GV+k];
    }
    float e0=0,e1=0,e2=0;
    #pragma unroll
    for (int k=0;k<10;k++){
      e0+=sm[SM_BW+k*3+0]*cv[k];
      e1+=sm[SM_BW+k*3+1]*cv[k];
      e2+=sm[SM_BW+k*3+2]*cv[k];
    }
    float ywa=sX[it2*16+0], ywb=sX[it2*16+1], ywc=sX[it2*16+2];
    #pragma unroll
    for (int i=0;i<3;i++)
      #pragma unroll
      for (int j=0;j<3;j++)
        out[gb2*9+i*3+j]=vn[1+3*j+i];
    out[73728+gb2*3+0]=ywa-(vn[1]*e0+vn[4]*e1+vn[7]*e2);
    out[73728+gb2*3+1]=ywb-(vn[2]*e0+vn[5]*e1+vn[8]*e2);
    out[73728+gb2*3+2]=ywc-(vn[3]*e0+vn[6]*e1+vn[9]*e2);
    #pragma unroll
    for (int k=0;k<10;k++)
      out[98304+gb2*10+k]=cv[k];
  }
}

extern "C" void kernel_launch(void* const* d_in, const int* in_sizes, int n_in,
                              void* d_out, int out_size, void* d_ws, size_t ws_size,
                              hipStream_t stream) {
  const float* y  = (const float*)d_in[0];   // (8192,3,100)
  const float* w  = (const float*)d_in[1];   // (100,1)
  const float* mk = (const float*)d_in[2];   // (10,3,100)
  float* out = (float*)d_out;                // R(8192*9) | t(8192*3) | c(8192*10)
  pace_fused<<<512, 256, 0, stream>>>(y, w, mk, out);
}